// Round 7
// baseline (113.905 us; speedup 1.0000x reference)
//
#include <hip/hip_runtime.h>
#include <math.h>

#define NB  4
#define NLQ 256
#define NLK 512
#define NH  256

// scale folded into projections: exp2(SC*(q+k)) = exp(2*(q+k))
#define SCALE_2LOG2E 2.885390081777927f
#define LOG2E        1.4426950408889634f

// ---------------------------------------------------------------------------
// Setup: W transposes (blocks 0..31) + per-batch mask compaction (32..35).
// ---------------------------------------------------------------------------
__global__ __launch_bounds__(256) void setup_kernel(
    const float* __restrict__ Wq, const float* __restrict__ Wk,
    const int* __restrict__ mask,
    float* __restrict__ Wtq, float* __restrict__ Wtk,
    int* __restrict__ act, int* __restrict__ nact)
{
    const int blk = blockIdx.x;
    const int t   = threadIdx.x;

    if (blk < 32) {
        // ---- transpose one 64x64 tile of Wq/Wk into Wtq/Wtk ----
        __shared__ float ts[64][65];
        const int m    = blk >> 4;               // 0: Wq, 1: Wk
        const int tile = blk & 15;
        const int h0 = (tile >> 2) * 64;
        const int c0 = (tile & 3) * 64;
        const float* W  = m ? Wk  : Wq;
        float*       Wt = m ? Wtk : Wtq;
        const int lr = t >> 4, lc = t & 15;
        #pragma unroll
        for (int i = 0; i < 4; ++i) {
            const int r = lr + 16 * i;
            const float4 d = *(const float4*)(W + (size_t)(h0 + r) * NH + c0 + lc * 4);
            ts[r][lc * 4 + 0] = d.x;
            ts[r][lc * 4 + 1] = d.y;
            ts[r][lc * 4 + 2] = d.z;
            ts[r][lc * 4 + 3] = d.w;
        }
        __syncthreads();
        #pragma unroll
        for (int i = 0; i < 4; ++i) {
            const int c = lr + 16 * i;
            float4 d;
            d.x = ts[lc * 4 + 0][c];
            d.y = ts[lc * 4 + 1][c];
            d.z = ts[lc * 4 + 2][c];
            d.w = ts[lc * 4 + 3][c];
            *(float4*)(Wt + (size_t)(c0 + c) * NH + h0 + lc * 4) = d;
        }
    } else if (blk < 32 + NB) {
        // ---- mask compaction for batch b ----
        const int b = blk - 32;
        __shared__ int wcnt[8], wpre[9];
        const int lane = t & 63, wave = t >> 6;
        const int k1 = t, k2 = t + 256;
        const int m1 = mask[b * NLK + k1];
        const int m2 = mask[b * NLK + k2];
        const unsigned long long below = (1ULL << lane) - 1ULL;
        const unsigned long long bal1 = __ballot(m1 != 0);
        const unsigned long long bal2 = __ballot(m2 != 0);
        const int r1 = __popcll(bal1 & below);
        const int r2 = __popcll(bal2 & below);
        if (lane == 0) { wcnt[wave] = __popcll(bal1); wcnt[4 + wave] = __popcll(bal2); }
        __syncthreads();
        if (t == 0) {
            int s = 0;
            #pragma unroll
            for (int w = 0; w < 8; ++w) { wpre[w] = s; s += wcnt[w]; }
            wpre[8] = s;
        }
        __syncthreads();
        const int na = wpre[8];
        if (m1) act[b * NLK + wpre[wave]     + r1] = k1;
        if (m2) act[b * NLK + wpre[4 + wave] + r2] = k2;
        if (k1 >= na) act[b * NLK + k1] = 0;     // safe tail for padded reads
        if (k2 >= na) act[b * NLK + k2] = 0;
        if (t == 0) nact[b] = na;
    }
}

// ---------------------------------------------------------------------------
// Fused projections (c-split across waves, coalesced Wt loads).
// XCD batch affinity: with round-robin block->XCD dispatch, b = idx&3 pins
// each batch's kp_ct/qp production to the XCDs that attn reads them on.
// Blocks 0..255: q rows (4/block) -> qp[b][lq][h] = exp2(scaled proj).
// Blocks 256..767: compact k slots (4/block, gathered via act) ->
//   kp_ct[b][h][j] compact-TRANSPOSED = exp2(scaled proj).
// ---------------------------------------------------------------------------
__global__ __launch_bounds__(256) void prep_kernel(
    const float* __restrict__ query, const float* __restrict__ key,
    const float* __restrict__ Wtq, const float* __restrict__ bq,
    const float* __restrict__ Wtk, const float* __restrict__ bk,
    const int* __restrict__ act, const int* __restrict__ nact,
    float* __restrict__ qp, float* __restrict__ kp_ct)
{
    const int blk  = blockIdx.x;
    const int t    = threadIdx.x;
    const int wave = t >> 6;
    const int lane = t & 63;

    __shared__ float  xs[4][NH];
    __shared__ float4 ps[4][4][64];
    __shared__ int    ridx[4];

    const float *Wt, *bias;
    int b = 0, j0 = 0, r0 = 0, na = 0;
    const bool isq = (blk < NB * NLQ / 4);

    if (isq) {
        b  = blk & 3;                            // XCD affinity
        r0 = b * NLQ + (blk >> 2) * 4;           // global q-row
        ((float4*)&xs[0][0])[t] = ((const float4*)(query + (size_t)r0 * NH))[t];
        Wt = Wtq; bias = bq;
    } else {
        const int idx = blk - 256;
        b  = idx & 3;                            // XCD affinity
        j0 = (idx >> 2) * 4;
        na = nact[b];
        if (j0 >= na) return;
        if (t < 4) ridx[t] = act[b * NLK + ((j0 + t < na) ? (j0 + t) : j0)];
        __syncthreads();
        const int r = t >> 6, c4 = t & 63;
        ((float4*)xs[r])[c4] =
            ((const float4*)(key + ((size_t)b * NLK + ridx[r]) * NH))[c4];
        Wt = Wtk; bias = bk;
    }
    __syncthreads();

    float4 acc[4];
    #pragma unroll
    for (int r = 0; r < 4; ++r) acc[r] = (float4){0.f, 0.f, 0.f, 0.f};

    const int cbase = wave * 64;
    #pragma unroll 4
    for (int cc = 0; cc < 64; ++cc) {
        const int c = cbase + cc;
        const float4 w = *(const float4*)(Wt + (size_t)c * NH + lane * 4);
        #pragma unroll
        for (int r = 0; r < 4; ++r) {
            const float xv = xs[r][c];             // LDS broadcast
            acc[r].x = fmaf(xv, w.x, acc[r].x);
            acc[r].y = fmaf(xv, w.y, acc[r].y);
            acc[r].z = fmaf(xv, w.z, acc[r].z);
            acc[r].w = fmaf(xv, w.w, acc[r].w);
        }
    }
    #pragma unroll
    for (int r = 0; r < 4; ++r) ps[wave][r][lane] = acc[r];
    __syncthreads();

    // combine: thread t -> row r = wave, h-quad l = lane
    const int r = wave, l = lane;
    const float4 p0 = ps[0][r][l], p1 = ps[1][r][l];
    const float4 p2 = ps[2][r][l], p3 = ps[3][r][l];
    const float4 bb = *(const float4*)(bias + l * 4);
    float4 o;
    o.x = (p0.x + p1.x + p2.x + p3.x + bb.x) * SCALE_2LOG2E;
    o.y = (p0.y + p1.y + p2.y + p3.y + bb.y) * SCALE_2LOG2E;
    o.z = (p0.z + p1.z + p2.z + p3.z + bb.z) * SCALE_2LOG2E;
    o.w = (p0.w + p1.w + p2.w + p3.w + bb.w) * SCALE_2LOG2E;
    // E-values: exp2 hoisted out of the attn inner loop
    o.x = __builtin_amdgcn_exp2f(o.x);
    o.y = __builtin_amdgcn_exp2f(o.y);
    o.z = __builtin_amdgcn_exp2f(o.z);
    o.w = __builtin_amdgcn_exp2f(o.w);

    if (isq) {
        *(float4*)(qp + (size_t)(r0 + r) * NH + l * 4) = o;
    } else if (j0 + r < na) {
        const int j = j0 + r;
        kp_ct[((size_t)b * NH + l * 4 + 0) * NLK + j] = o.x;
        kp_ct[((size_t)b * NH + l * 4 + 1) * NLK + j] = o.y;
        kp_ct[((size_t)b * NH + l * 4 + 2) * NLK + j] = o.z;
        kp_ct[((size_t)b * NH + l * 4 + 3) * NLK + j] = o.w;
    }
}

// ---------------------------------------------------------------------------
// Fused attn. Block = 512 threads (8 waves), ONE q row, grid = 1024.
// -> 4 blocks/CU x 8 waves = 32 waves/CU = 8 waves/SIMD (hardware cap),
// 2x R4/R6 residency; barrier scope back to 512 threads. L2 traffic
// doubles vs R4 -- proven irrelevant by the R5/R6 null result.
// XCD batch affinity: b = blk&3 (blk ≡ x mod 8 per XCD -> blk&3 constant).
// Score: wave = h-octant (32 c); lane owns slots 4l..4l+3 and (na>256,
// block-uniform) 256+4l..256+4l+3. Unused upper half stays zero ->
// masked at combine. Partials [8 oct][512 slots] = 16 KB.
// Combine: thread t = slot t, stride-1 conflict-free, masked by na.
// Softmax: wave 0 (512 slots). Output: j ≡ wave mod 8, one float4 value
// load; 8-way LDS reduce (reusing the partial buffer). Per-slot reduction
// tree identical to R4 -> bit-identical results.
// ---------------------------------------------------------------------------
__global__ __launch_bounds__(512) void attn_kernel(
    const float* __restrict__ qp, const float* __restrict__ kp_ct,
    const float* __restrict__ value, const int* __restrict__ mask,
    const int* __restrict__ act, const int* __restrict__ nact,
    const float* __restrict__ vvec,
    float* __restrict__ out_o, float* __restrict__ out_w)
{
    __shared__ float sc[NLK];          // 2 KB scores/weights
    __shared__ int   actl[NLK];        // 2 KB
    __shared__ float eqs[NH];          // 1 KB
    __shared__ float vvs[NH];          // 1 KB
    __shared__ float4 buf4[1024];      // 16 KB: score partials [8][512]f / out partials [512]f4

    const int blk  = blockIdx.x;
    const int b    = blk & 3;                // XCD batch affinity
    const int q    = blk >> 2;               // q row 0..255
    const int t    = threadIdx.x;            // 0..511
    const int lane = t & 63;
    const int wave = t >> 6;                 // 0..7

    const int na = nact[b];
    actl[t] = (t < na) ? act[b * NLK + t] : 0;
    if (t < NH) {
        eqs[t] = qp[(size_t)(b * NLQ + q) * NH + t];
        vvs[t] = vvec[t];
    }

    // zero masked out_w slots for this row (scatter fills actives)
    float* wrow = out_w + (size_t)(b * NLQ + q) * NLK;
    if (!mask[b * NLK + t]) wrow[t] = 0.f;
    __syncthreads();                         // eqs/vvs/actl ready

    const int cb = wave * 32;                // h-octant for this wave
    const float* kb = kp_ct + ((size_t)b * NH + cb) * NLK;
    const float* eq = &eqs[cb];
    const float* vv = &vvs[cb];

    // ---- single score pass: slots 4l (and 256+4l when na>256) ----
    float4 a0 = {0.f, 0.f, 0.f, 0.f};        // slots 4*lane ..
    float4 a1 = {0.f, 0.f, 0.f, 0.f};        // slots 256+4*lane .. (stays 0 if na<=256)
    if (na > 256) {
        #pragma unroll 4
        for (int c = 0; c < 32; ++c) {
            const float4 k1 = *(const float4*)(kb + (size_t)c * NLK + 4 * lane);
            const float4 k2 = *(const float4*)(kb + (size_t)c * NLK + 256 + 4 * lane);
            const float e  = eq[c];           // wave-uniform LDS broadcast
            const float vh = vv[c];
            a0.x = fmaf(vh, __builtin_amdgcn_rcpf(fmaf(e, k1.x, 1.f)), a0.x);
            a0.y = fmaf(vh, __builtin_amdgcn_rcpf(fmaf(e, k1.y, 1.f)), a0.y);
            a0.z = fmaf(vh, __builtin_amdgcn_rcpf(fmaf(e, k1.z, 1.f)), a0.z);
            a0.w = fmaf(vh, __builtin_amdgcn_rcpf(fmaf(e, k1.w, 1.f)), a0.w);
            a1.x = fmaf(vh, __builtin_amdgcn_rcpf(fmaf(e, k2.x, 1.f)), a1.x);
            a1.y = fmaf(vh, __builtin_amdgcn_rcpf(fmaf(e, k2.y, 1.f)), a1.y);
            a1.z = fmaf(vh, __builtin_amdgcn_rcpf(fmaf(e, k2.z, 1.f)), a1.z);
            a1.w = fmaf(vh, __builtin_amdgcn_rcpf(fmaf(e, k2.w, 1.f)), a1.w);
        }
    } else {
        #pragma unroll 4
        for (int c = 0; c < 32; ++c) {
            const float4 k1 = *(const float4*)(kb + (size_t)c * NLK + 4 * lane);
            const float e  = eq[c];
            const float vh = vv[c];
            a0.x = fmaf(vh, __builtin_amdgcn_rcpf(fmaf(e, k1.x, 1.f)), a0.x);
            a0.y = fmaf(vh, __builtin_amdgcn_rcpf(fmaf(e, k1.y, 1.f)), a0.y);
            a0.z = fmaf(vh, __builtin_amdgcn_rcpf(fmaf(e, k1.z, 1.f)), a0.z);
            a0.w = fmaf(vh, __builtin_amdgcn_rcpf(fmaf(e, k1.w, 1.f)), a0.w);
        }
    }
    // partials as float[8][512]: float4 idx = wave*128 + half*64 + lane
    buf4[wave * 128 + lane]      = a0;
    buf4[wave * 128 + 64 + lane] = a1;
    __syncthreads();

    // ---- combine: thread t -> slot t; 8 octant adds, stride-1 ----
    {
        const float* pf = (const float*)buf4;
        float s = 0.f;
        #pragma unroll
        for (int o = 0; o < 8; ++o) s += pf[o * 512 + t];
        sc[t] = (t < na) ? -2.f * s : -INFINITY;
    }
    __syncthreads();

    // ---- softmax: wave 0, 512 slots ----
    if (wave == 0) {
        float vals[8];
        float m = -INFINITY;
        #pragma unroll
        for (int j8 = 0; j8 < 8; ++j8) {
            vals[j8] = sc[lane + j8 * 64];
            m = fmaxf(m, vals[j8]);
        }
        #pragma unroll
        for (int s = 32; s >= 1; s >>= 1)
            m = fmaxf(m, __shfl_xor(m, s, 64));
        float sum = 0.0f;
        #pragma unroll
        for (int j8 = 0; j8 < 8; ++j8) {
            vals[j8] = __builtin_amdgcn_exp2f((vals[j8] - m) * LOG2E);
            sum += vals[j8];
        }
        #pragma unroll
        for (int s = 32; s >= 1; s >>= 1)
            sum += __shfl_xor(sum, s, 64);
        const float inv = __builtin_amdgcn_rcpf(sum);
        #pragma unroll
        for (int j8 = 0; j8 < 8; ++j8) {
            const int jj = lane + j8 * 64;
            const float w = vals[j8] * inv;
            sc[jj] = w;                       // 0 for jj >= na
            if (jj < na) wrow[actl[jj]] = w;  // masked slots stay 0
        }
    }
    __syncthreads();

    // ---- output: j ≡ wave (mod 8); one float4 value load; 8-way reduce ----
    {
        const float* vb = value + (size_t)b * NLK * NH + lane * 4;
        float4 o0 = {0.f, 0.f, 0.f, 0.f};
        #pragma unroll 4
        for (int j = wave; j < na; j += 8) {
            const float w0 = sc[j];           // wave-uniform LDS broadcast
            const int   rj = actl[j];
            const float4 v4 = *(const float4*)(vb + (size_t)rj * NH);
            o0.x = fmaf(w0, v4.x, o0.x); o0.y = fmaf(w0, v4.y, o0.y);
            o0.z = fmaf(w0, v4.z, o0.z); o0.w = fmaf(w0, v4.w, o0.w);
        }
        __syncthreads();                     // buf4 combine-reads done; reuse
        buf4[t] = o0;
        __syncthreads();
        if (t < 64) {
            float4 o = buf4[t];
            #pragma unroll
            for (int w = 1; w < 8; ++w) {
                const float4 s = buf4[w * 64 + t];
                o.x += s.x; o.y += s.y; o.z += s.z; o.w += s.w;
            }
            *(float4*)(out_o + (size_t)(b * NLQ + q) * NH + t * 4) = o;
        }
    }
}

// ---------------------------------------------------------------------------
extern "C" void kernel_launch(void* const* d_in, const int* in_sizes, int n_in,
                              void* d_out, int out_size, void* d_ws, size_t ws_size,
                              hipStream_t stream) {
    const float* query = (const float*)d_in[0];
    const float* key   = (const float*)d_in[1];
    const float* value = (const float*)d_in[2];
    const int*   mask  = (const int*)  d_in[3];
    const float* Wq    = (const float*)d_in[4];
    const float* bq    = (const float*)d_in[5];
    const float* Wk    = (const float*)d_in[6];
    const float* bk    = (const float*)d_in[7];
    const float* v     = (const float*)d_in[8];
    // d_in[9] (bv) drops out of softmax -> unused

    float* out_o = (float*)d_out;                     // [4,256,256]
    float* out_w = out_o + NB * NLQ * NH;             // [4,256,512]

    float* qp    = (float*)d_ws;                      // [4,256,256] Eq
    float* kp_ct = qp + NB * NLQ * NH;                // [4,256,512] Ek compact-T
    int*   act   = (int*)(kp_ct + NB * NH * NLK);     // [4,512]
    int*   nact  = act + NB * NLK;                    // [4]

    const size_t base = (size_t)(NB * NLQ * NH) + (size_t)(NB * NH * NLK)
                      + NB * NLK + NB;                // floats+ints consumed
    float* wtq;
    if (ws_size >= (base + 2 * NH * NH) * sizeof(float)) {
        wtq = (float*)d_ws + base;                    // workspace tail
    } else {
        // park W^T in the out_w tail; attn (after prep) overwrites out_w
        wtq = out_w + (size_t)NB * NLQ * NLK - 2 * NH * NH;
    }
    float* wtk = wtq + NH * NH;

    setup_kernel<<<36, 256, 0, stream>>>(Wq, Wk, mask, wtq, wtk, act, nact);
    prep_kernel<<<NB * NLQ / 4 + NB * NLK / 4, 256, 0, stream>>>(
        query, key, wtq, bq, wtk, bk, act, nact, qp, kp_ct);
    attn_kernel<<<NB * NLQ, 512, 0, stream>>>(
        qp, kp_ct, value, mask, act, nact, v, out_o, out_w);
}